// Round 4
// baseline (1475.835 us; speedup 1.0000x reference)
//
#include <hip/hip_runtime.h>
#include <stdint.h>

#define DIMK 4096
#define HD 128
#define NH 32
#define SEQL 2048
#define BSZN 2
#define NROWS (BSZN*SEQL)   // 4096

typedef __bf16 bf16x8 __attribute__((ext_vector_type(8)));
typedef float f32x4 __attribute__((ext_vector_type(4)));
typedef unsigned short u16;
typedef unsigned int u32;

__device__ __forceinline__ float bf2f(u16 h){
  u32 u = ((u32)h) << 16; float f;
  __builtin_memcpy(&f, &u, 4); return f;
}
// round-to-nearest-even f32 -> bf16
__device__ __forceinline__ u16 f2bf(float f){
  u32 u; __builtin_memcpy(&u, &f, 4);
  return (u16)((u + 0x7fffu + ((u >> 16) & 1u)) >> 16);
}

// async global->LDS, 16B/lane; LDS dest wave-uniform base + lane*16B
// (used ONLY in the m97-pattern GEMM below, exactly 4 outstanding per wave)
__device__ __forceinline__ void gld_lds16(const void* g, void* l){
  __builtin_amdgcn_global_load_lds(
      (__attribute__((address_space(1))) void*)(uintptr_t)g,
      (__attribute__((address_space(3))) void*)(uintptr_t)l, 16, 0, 0);
}

// ---------------------------------------------------------------------------
// GEMM (m97 recipe, replay-stability proven by m103's 50-iter runs):
// C[m,n] = sum_k A[m,k]*B[n,k], A/B bf16 row-major 4096x4096.
// 128x128 tile, BK=32, 4 waves (2x2), 16x16x32 bf16 MFMA, 4x4 acc/wave.
// OUTF32=0: bf16 C; OUTF32=1: f32 C.
// ---------------------------------------------------------------------------
template<int OUTF32>
__device__ __forceinline__ void gemm_core(const u16* __restrict__ A,
                                          const u16* __restrict__ B,
                                          void* __restrict__ Cv,
                                          short* As, short* Bs)
{
  const int tid  = threadIdx.x;
  const int wave = tid >> 6, lane = tid & 63;
  const int wm = wave >> 1, wn = wave & 1;
  const int g = lane >> 4, c16 = lane & 15;
  const int m0 = blockIdx.x * 128, n0 = blockIdx.y * 128;

  const u16* ga[2]; const u16* gb[2]; short* la[2]; short* lb[2];
  #pragma unroll
  for (int p = 0; p < 2; ++p){
    int c = wave*2 + p;
    int row = c*16 + (lane >> 2);
    int col = (lane & 3) * 8;
    ga[p] = A + (size_t)(m0 + row)*DIMK + col;
    gb[p] = B + (size_t)(n0 + row)*DIMK + col;
    la[p] = As + c*512;
    lb[p] = Bs + c*512;
  }

  f32x4 acc[4][4];
  #pragma unroll
  for (int i = 0; i < 4; ++i)
    #pragma unroll
    for (int j = 0; j < 4; ++j)
      acc[i][j] = (f32x4){0.f, 0.f, 0.f, 0.f};

  for (int k0 = 0; k0 < DIMK; k0 += 32){
    #pragma unroll
    for (int p = 0; p < 2; ++p){
      gld_lds16(ga[p], la[p]);
      gld_lds16(gb[p], lb[p]);
      ga[p] += 32; gb[p] += 32;
    }
    __syncthreads();   // vmcnt(0) drain before barrier makes staged data visible
    bf16x8 af[4], bfr[4];
    #pragma unroll
    for (int i = 0; i < 4; ++i)
      af[i] = *(const bf16x8*)(As + (wm*64 + i*16 + c16)*32 + g*8);
    #pragma unroll
    for (int j = 0; j < 4; ++j)
      bfr[j] = *(const bf16x8*)(Bs + (wn*64 + j*16 + c16)*32 + g*8);
    #pragma unroll
    for (int i = 0; i < 4; ++i)
      #pragma unroll
      for (int j = 0; j < 4; ++j)
        acc[i][j] = __builtin_amdgcn_mfma_f32_16x16x32_bf16(af[i], bfr[j], acc[i][j], 0, 0, 0);
    __syncthreads();   // protect LDS before next-iter staging
  }

  // C/D layout (m89/m91 verified): col = lane&15, row = (lane>>4)*4 + reg
  if constexpr (OUTF32 == 0){
    u16* C = (u16*)Cv;
    #pragma unroll
    for (int i = 0; i < 4; ++i){
      int mrow = m0 + wm*64 + i*16 + g*4;
      #pragma unroll
      for (int j = 0; j < 4; ++j){
        int ncol = n0 + wn*64 + j*16 + c16;
        #pragma unroll
        for (int r = 0; r < 4; ++r)
          C[(size_t)(mrow + r)*DIMK + ncol] = f2bf(acc[i][j][r]);
      }
    }
  } else {
    float* C = (float*)Cv;
    #pragma unroll
    for (int i = 0; i < 4; ++i){
      int mrow = m0 + wm*64 + i*16 + g*4;
      #pragma unroll
      for (int j = 0; j < 4; ++j){
        int ncol = n0 + wn*64 + j*16 + c16;
        #pragma unroll
        for (int r = 0; r < 4; ++r)
          C[(size_t)(mrow + r)*DIMK + ncol] = acc[i][j][r];
      }
    }
  }
}

__global__ __launch_bounds__(256) void gemm_bf16_kernel(const u16* __restrict__ A,
    const u16* __restrict__ B, u16* __restrict__ C)
{
  __shared__ short As[128*32];
  __shared__ short Bs[128*32];
  gemm_core<0>(A, B, C, As, Bs);
}

__global__ __launch_bounds__(256) void gemm_f32_kernel(const u16* __restrict__ A,
    const u16* __restrict__ B, float* __restrict__ C)
{
  __shared__ short As[128*32];
  __shared__ short Bs[128*32];
  gemm_core<1>(A, B, C, As, Bs);
}

// f32 -> bf16 bulk convert (RNE), 8 elems/thread
__global__ __launch_bounds__(256) void cvt_kernel(const float* __restrict__ src,
                                                  u16* __restrict__ dst, int n8)
{
  int t = blockIdx.x*256 + threadIdx.x;
  if (t >= n8) return;
  const f32x4* s = (const f32x4*)src + (size_t)t*2;
  f32x4 a = s[0], b = s[1];
  ushort4 lo, hi;
  lo.x = f2bf(a[0]); lo.y = f2bf(a[1]); lo.z = f2bf(a[2]); lo.w = f2bf(a[3]);
  hi.x = f2bf(b[0]); hi.y = f2bf(b[1]); hi.z = f2bf(b[2]); hi.w = f2bf(b[3]);
  ushort4* d = (ushort4*)dst + (size_t)t*2;
  d[0] = lo; d[1] = hi;
}

// ---------------------------------------------------------------------------
// V (B,S,DIM row-major) -> V^T ([b][h][d][s]); 64x64 LDS tile per block
// ---------------------------------------------------------------------------
__global__ __launch_bounds__(256) void transpose_kernel(const u16* __restrict__ v,
                                                        u16* __restrict__ vt)
{
  __shared__ u16 tile[64][72];
  const int t  = threadIdx.x;
  const int s0 = blockIdx.x * 64;
  const int d0 = blockIdx.y * 64;
  const int bh = blockIdx.z;
  const int b = bh >> 5, h = bh & 31;

  #pragma unroll
  for (int i = 0; i < 4; ++i){
    int row = i*16 + (t >> 4);
    int cc  = (t & 15) * 4;
    uint2 val = *(const uint2*)(v + (size_t)(b*SEQL + s0 + row)*DIMK + h*HD + d0 + cc);
    const u16* p4 = (const u16*)&val;
    #pragma unroll
    for (int j = 0; j < 4; ++j) tile[cc + j][row] = p4[j];
  }
  __syncthreads();
  #pragma unroll
  for (int i = 0; i < 4; ++i){
    int drow = i*16 + (t >> 4);
    int sc   = (t & 15) * 4;
    uint2 o; u16* po = (u16*)&o;
    #pragma unroll
    for (int j = 0; j < 4; ++j) po[j] = tile[drow][sc + j];
    *(uint2*)(vt + ((size_t)(b*NH + h)*HD + d0 + drow)*SEQL + s0 + sc) = o;
  }
}

// ---------------------------------------------------------------------------
// RoPE (interleaved pairs), OUT-OF-PLACE: qsrc->qdst, ksrc->kdst; freqs f32
// ---------------------------------------------------------------------------
__global__ __launch_bounds__(256) void rope_kernel(const u16* __restrict__ qsrc,
    const u16* __restrict__ ksrc, u16* __restrict__ qdst, u16* __restrict__ kdst,
    const float* __restrict__ fc, const float* __restrict__ fs)
{
  const size_t PER = (size_t)NROWS * DIMK / 8;
  size_t t = (size_t)blockIdx.x * 256 + threadIdx.x;
  const u16* src = qsrc; u16* dst = qdst;
  if (t >= PER){ src = ksrc; dst = kdst; t -= PER; }
  size_t e0 = t * 8;
  int row = (int)(e0 >> 12);
  int col = (int)(e0 & (DIMK-1));
  int s  = row & (SEQL-1);
  int i0 = (col & (HD-1)) >> 1;

  uint4 raw = *(const uint4*)(src + e0);
  u16* xs = (u16*)&raw;
  f32x4 c4 = *(const f32x4*)(fc + s*64 + i0);
  f32x4 s4 = *(const f32x4*)(fs + s*64 + i0);
  #pragma unroll
  for (int j = 0; j < 4; ++j){
    float e = bf2f(xs[2*j]), o = bf2f(xs[2*j+1]);
    float c = c4[j], sn = s4[j];
    xs[2*j]   = f2bf(e*c - o*sn);
    xs[2*j+1] = f2bf(e*sn + o*c);
  }
  *(uint4*)(dst + e0) = raw;
}

// ---------------------------------------------------------------------------
// Flash attention, causal. 4 waves = 128 Q rows/block. Bc=64 K-cols/step.
// Explicit LDS staging (padded strides). fp32 online softmax in registers.
// P round-trips through LDS with an explicit __syncthreads() between the
// cross-lane scatter writes and the A-fragment reads (race fix, round 4).
// ---------------------------------------------------------------------------
__global__ __launch_bounds__(256) void flash_kernel(const u16* __restrict__ Q,
    const u16* __restrict__ K, const u16* __restrict__ Vt, u16* __restrict__ AO)
{
  __shared__ short Ks[64*136];    // [s][d], row stride 136
  __shared__ short Vs[128*72];    // [d][s], row stride 72
  __shared__ short Ps[4*32*72];   // per-wave P strips, stride 72

  const int qt = (int)(gridDim.x - 1) - (int)blockIdx.x;  // heavy diagonal first
  const int bh = blockIdx.y;
  const int b = bh >> 5, h = bh & 31;
  const int tid = threadIdx.x;
  const int wave = tid >> 6, lane = tid & 63;
  const int g = lane >> 4, c16 = lane & 15;
  const int qr0 = qt*128 + wave*32;

  bf16x8 qa[2][4];
  #pragma unroll
  for (int rt = 0; rt < 2; ++rt){
    const u16* qp = Q + (size_t)(b*SEQL + qr0 + rt*16 + c16)*DIMK + h*HD + g*8;
    #pragma unroll
    for (int kc = 0; kc < 4; ++kc)
      qa[rt][kc] = *(const bf16x8*)(qp + kc*32);
  }

  f32x4 oacc[2][8];
  #pragma unroll
  for (int rt = 0; rt < 2; ++rt)
    #pragma unroll
    for (int dt = 0; dt < 8; ++dt)
      oacc[rt][dt] = (f32x4){0.f, 0.f, 0.f, 0.f};
  float m_st[2][4], l_st[2][4];
  #pragma unroll
  for (int rt = 0; rt < 2; ++rt)
    #pragma unroll
    for (int r = 0; r < 4; ++r){ m_st[rt][r] = -1e30f; l_st[rt][r] = 0.f; }

  const u16* kb = K  + (size_t)(b*SEQL)*DIMK + h*HD;
  const u16* vb = Vt + (size_t)(b*NH + h)*HD*SEQL;
  short* Pw = Ps + wave*(32*72);

  const int nsteps = 2*(qt + 1);
  for (int kt = 0; kt < nsteps; ++kt){
    const int s0 = kt*64;
    __syncthreads();              // prior iter's Ks/Vs/Ps reads complete
    #pragma unroll
    for (int it = 0; it < 4; ++it){
      int idx = it*256 + tid;
      int r  = idx >> 4, ch = idx & 15;
      *(bf16x8*)(Ks + r*136 + ch*8) =
          *(const bf16x8*)(kb + (size_t)(s0 + r)*DIMK + ch*8);
    }
    #pragma unroll
    for (int it = 0; it < 4; ++it){
      int idx = it*256 + tid;
      int d  = idx >> 3, sch = idx & 7;
      *(bf16x8*)(Vs + d*72 + sch*8) =
          *(const bf16x8*)(vb + (size_t)d*SEQL + s0 + sch*8);
    }
    __syncthreads();

    // S = Q K^T
    f32x4 sacc[2][4];
    #pragma unroll
    for (int rt = 0; rt < 2; ++rt)
      #pragma unroll
      for (int ct = 0; ct < 4; ++ct)
        sacc[rt][ct] = (f32x4){0.f, 0.f, 0.f, 0.f};
    #pragma unroll
    for (int kc = 0; kc < 4; ++kc){
      #pragma unroll
      for (int ct = 0; ct < 4; ++ct){
        bf16x8 bfr = *(const bf16x8*)(Ks + (ct*16 + c16)*136 + (g + 4*kc)*8);
        sacc[0][ct] = __builtin_amdgcn_mfma_f32_16x16x32_bf16(qa[0][kc], bfr, sacc[0][ct], 0, 0, 0);
        sacc[1][ct] = __builtin_amdgcn_mfma_f32_16x16x32_bf16(qa[1][kc], bfr, sacc[1][ct], 0, 0, 0);
      }
    }

    // scale + causal mask (C layout: row = g*4+r, col = c16)
    const float scale = 0.08838834764831845f;
    #pragma unroll
    for (int rt = 0; rt < 2; ++rt){
      int rowb = qr0 + rt*16 + g*4;
      #pragma unroll
      for (int ct = 0; ct < 4; ++ct){
        int scol = s0 + ct*16 + c16;
        #pragma unroll
        for (int r = 0; r < 4; ++r){
          float v = sacc[rt][ct][r] * scale;
          sacc[rt][ct][r] = (scol <= rowb + r) ? v : -1e30f;
        }
      }
    }

    // online softmax update (row state replicated across the 16-lane group)
    #pragma unroll
    for (int rt = 0; rt < 2; ++rt){
      #pragma unroll
      for (int r = 0; r < 4; ++r){
        float mx = fmaxf(fmaxf(sacc[rt][0][r], sacc[rt][1][r]),
                         fmaxf(sacc[rt][2][r], sacc[rt][3][r]));
        #pragma unroll
        for (int off = 1; off < 16; off <<= 1)
          mx = fmaxf(mx, __shfl_xor(mx, off));
        float mn = fmaxf(m_st[rt][r], mx);
        float al = __expf(m_st[rt][r] - mn);
        m_st[rt][r] = mn;
        float sum = 0.f;
        #pragma unroll
        for (int ct = 0; ct < 4; ++ct){
          float pv = __expf(sacc[rt][ct][r] - mn);
          sacc[rt][ct][r] = pv;
          sum += pv;
        }
        #pragma unroll
        for (int off = 1; off < 16; off <<= 1)
          sum += __shfl_xor(sum, off);
        l_st[rt][r] = l_st[rt][r]*al + sum;
        #pragma unroll
        for (int dt = 0; dt < 8; ++dt)
          oacc[rt][dt][r] *= al;
      }
    }

    // P -> LDS strip (cross-lane scatter)
    #pragma unroll
    for (int rt = 0; rt < 2; ++rt)
      #pragma unroll
      for (int ct = 0; ct < 4; ++ct)
        #pragma unroll
        for (int r = 0; r < 4; ++r)
          Pw[(rt*16 + g*4 + r)*72 + ct*16 + c16] = (short)f2bf(sacc[rt][ct][r]);

    __syncthreads();   // NEW (round 4): make P writes visible before A-frag reads

    // O += P V
    #pragma unroll
    for (int kc2 = 0; kc2 < 2; ++kc2){
      bf16x8 pf0 = *(const bf16x8*)(Pw + (c16)*72      + g*8 + kc2*32);
      bf16x8 pf1 = *(const bf16x8*)(Pw + (16 + c16)*72 + g*8 + kc2*32);
      #pragma unroll
      for (int dt = 0; dt < 8; ++dt){
        bf16x8 vf = *(const bf16x8*)(Vs + (dt*16 + c16)*72 + (g + 4*kc2)*8);
        oacc[0][dt] = __builtin_amdgcn_mfma_f32_16x16x32_bf16(pf0, vf, oacc[0][dt], 0, 0, 0);
        oacc[1][dt] = __builtin_amdgcn_mfma_f32_16x16x32_bf16(pf1, vf, oacc[1][dt], 0, 0, 0);
      }
    }
  }

  // normalize + store (B,S,DIM)
  #pragma unroll
  for (int rt = 0; rt < 2; ++rt){
    float inv[4];
    #pragma unroll
    for (int r = 0; r < 4; ++r) inv[r] = 1.0f / l_st[rt][r];
    #pragma unroll
    for (int dt = 0; dt < 8; ++dt){
      #pragma unroll
      for (int r = 0; r < 4; ++r){
        int qrow = qr0 + rt*16 + g*4 + r;
        int col  = h*HD + dt*16 + c16;
        AO[(size_t)(b*SEQL + qrow)*DIMK + col] = f2bf(oacc[rt][dt][r] * inv[r]);
      }
    }
  }
}

extern "C" void kernel_launch(void* const* d_in, const int* in_sizes, int n_in,
                              void* d_out, int out_size, void* d_ws, size_t ws_size,
                              hipStream_t stream)
{
  const float* x  = (const float*)d_in[0];
  const float* wq = (const float*)d_in[1];
  const float* wk = (const float*)d_in[2];
  const float* wv = (const float*)d_in[3];
  const float* wo = (const float*)d_in[4];
  const float* fc = (const float*)d_in[5];
  const float* fs = (const float*)d_in[6];
  float* out = (float*)d_out;

  const size_t TEN  = (size_t)NROWS * DIMK;    // 16,777,216 elems
  const size_t TENB = TEN * sizeof(u16);       // 32 MiB
  const int N8 = (int)(TEN / 8);

  const dim3 G(32, 32), B256(256);

  if (ws_size >= 8 * TENB){
    // --- all scratch in ws; d_out written only by the final GEMM ---
    u16* xb   = (u16*)d_ws;
    u16* wb   = xb   + TEN;
    u16* qb   = wb   + TEN;
    u16* kb   = qb   + TEN;
    u16* vraw = kb   + TEN;
    u16* vtb  = vraw + TEN;
    u16* qro  = vtb  + TEN;
    u16* kro  = qro  + TEN;
    cvt_kernel<<<dim3(8192), B256, 0, stream>>>(x,  xb, N8);
    cvt_kernel<<<dim3(8192), B256, 0, stream>>>(wq, wb, N8);
    gemm_bf16_kernel<<<G, B256, 0, stream>>>(xb, wb, qb);
    cvt_kernel<<<dim3(8192), B256, 0, stream>>>(wk, wb, N8);
    gemm_bf16_kernel<<<G, B256, 0, stream>>>(xb, wb, kb);
    cvt_kernel<<<dim3(8192), B256, 0, stream>>>(wv, wb, N8);
    gemm_bf16_kernel<<<G, B256, 0, stream>>>(xb, wb, vraw);
    transpose_kernel<<<dim3(32, 2, 64), B256, 0, stream>>>(vraw, vtb);
    rope_kernel<<<dim3(16384), B256, 0, stream>>>(qb, kb, qro, kro, fc, fs);
    flash_kernel<<<dim3(16, 64), B256, 0, stream>>>(qro, kro, vtb, vraw); // AO->vraw
    cvt_kernel<<<dim3(8192), B256, 0, stream>>>(wo, xb, N8);              // xb dead
    gemm_f32_kernel<<<G, B256, 0, stream>>>(vraw, xb, out);
  } else if (ws_size >= 4 * TENB){
    // --- 128 MiB fallback: xb/wb live in d_out until the final GEMM ---
    u16* xb  = (u16*)d_out;
    u16* wb  = xb + TEN;
    u16* qb  = (u16*)d_ws;
    u16* kb  = qb + TEN;
    u16* vtb = kb + TEN;
    u16* s3  = vtb + TEN;                       // Vraw, then roped-Q
    cvt_kernel<<<dim3(8192), B256, 0, stream>>>(x,  xb, N8);
    cvt_kernel<<<dim3(8192), B256, 0, stream>>>(wq, wb, N8);
    gemm_bf16_kernel<<<G, B256, 0, stream>>>(xb, wb, qb);
    cvt_kernel<<<dim3(8192), B256, 0, stream>>>(wk, wb, N8);
    gemm_bf16_kernel<<<G, B256, 0, stream>>>(xb, wb, kb);
    cvt_kernel<<<dim3(8192), B256, 0, stream>>>(wv, wb, N8);
    gemm_bf16_kernel<<<G, B256, 0, stream>>>(xb, wb, s3);                 // Vraw
    transpose_kernel<<<dim3(32, 2, 64), B256, 0, stream>>>(s3, vtb);
    rope_kernel<<<dim3(16384), B256, 0, stream>>>(qb, kb, s3, xb, fc, fs); // qro=s3, kro=xb
    flash_kernel<<<dim3(16, 64), B256, 0, stream>>>(s3, xb, vtb, qb);      // AO->qb
    cvt_kernel<<<dim3(8192), B256, 0, stream>>>(wo, kb, N8);               // kb dead
    gemm_f32_kernel<<<G, B256, 0, stream>>>(qb, kb, out);
  }
}